// Round 4
// baseline (415.852 us; speedup 1.0000x reference)
//
#include <hip/hip_runtime.h>
#include <stdint.h>

#define DEVI __device__ __forceinline__

typedef __bf16 bf16x8 __attribute__((ext_vector_type(8)));
typedef float  floatx4 __attribute__((ext_vector_type(4)));

// B=8, S=2048, H=1024. M = B*S = 16384.
// ws: Q @0 (32MiB, pre-scaled 1/32) | K @+32M | Vt @+64M ([8][1024 d][2048 k])
//     lvec @+96M (f32[16384]) | P @+96M+64K (bf16 [8][2048][2048]);
//     P region overlays Xb (32MiB) + Wt (6MiB), dead before P written.
//
// Round-8: round-7 failed from a SINGLE bug — LDS arrays declared 2*128*64
// (32KB) while the double-buffer stride BUF=16384 ushorts assumes a full
// 256x64 buffer (32KB) per buffer: writes into buffer 1 overflowed AsF into
// BsF -> NaN. Correct size is 2*256*64 ushorts (64KB) per array, 128KB total
// (matches round-6's LDS_Block_Size=131072). Everything else identical to
// round-7; hoisting algebra re-audited vs the verified round-6 kernel:
//   - frag swizzle (rr&7)==l15&7 for ALL reads; cc1 = cc0^4 == (4+quad)^...
//   - stage swizzle u==(l&7)^(l>>3) for ALL slots (row bases %8==0)
//   - stream kt-sequences: AH0: 0,1,kt+2...; AH1: 0,kt+1...; B symmetric
//   - vmcnt(4)@p4 retires tile t+1's 4 halves; tails vmcnt(0)
// Phases (from round-6, measured 408us):
//   p1: reads A0+B0 (12), stage AH1(t+1)->bn   p2: reads B1 (4), stage BH1(t+1)->bn
//   p3: reads A1 (8),     stage AH0(t+2)->bc   p4: no reads,    stage BH0(t+2)->bc
// (Kept: do NOT replace with 32x32 MFMA, LDS-staged epilogue, or B-direct
// loads — all measured regressions in earlier rounds.)

DEVI unsigned short f2bf(float f) {
  union { float f; uint32_t u; } x; x.f = f;
  return (unsigned short)((x.u + 0x7fffu + ((x.u >> 16) & 1u)) >> 16);
}
DEVI float bf2f(unsigned short s) {
  union { uint32_t u; float f; } x; x.u = ((uint32_t)s) << 16;
  return x.f;
}

// ---------------- fused prep: X->bf16, 3x W transpose->bf16, lvec=0 ----------------
__global__ __launch_bounds__(256) void k_prep(
    const float* __restrict__ X, unsigned short* __restrict__ Xb,
    const float* __restrict__ Wq, const float* __restrict__ Wk,
    const float* __restrict__ Wv, unsigned short* __restrict__ Wt,
    float* __restrict__ lvec) {
  __shared__ float tile[64][65];
  int bx = blockIdx.x, t = threadIdx.x;
  if (bx < 16384) {                 // convert X: 4194304 float4 groups
    int i = bx * 256 + t;
    float4 v = ((const float4*)X)[i];
    ushort4 o;
    o.x = f2bf(v.x); o.y = f2bf(v.y); o.z = f2bf(v.z); o.w = f2bf(v.w);
    ((ushort4*)Xb)[i] = o;
  } else if (bx < 17152) {          // 3 x 256 transpose blocks
    int idx = bx - 16384;
    int sel = idx >> 8, b2 = idx & 255;
    const float* W = sel == 0 ? Wq : (sel == 1 ? Wk : Wv);
    unsigned short* Wo = Wt + ((size_t)sel << 20);
    int h0 = (b2 & 15) * 64, d0 = (b2 >> 4) * 64;
#pragma unroll
    for (int i = 0; i < 16; ++i) {
      int idx2 = i * 256 + t; int r = idx2 >> 6, c = idx2 & 63;
      tile[r][c] = W[(size_t)(h0 + r) * 1024 + d0 + c];
    }
    __syncthreads();
#pragma unroll
    for (int i = 0; i < 16; ++i) {
      int idx2 = i * 256 + t; int r = idx2 >> 6, c = idx2 & 63;
      Wo[(size_t)(d0 + r) * 1024 + h0 + c] = f2bf(tile[c][r]);
    }
  } else {                          // zero lvec (16384 f32)
    float4 z4 = {0.f, 0.f, 0.f, 0.f};
#pragma unroll
    for (int i = 0; i < 16; ++i) ((float4*)lvec)[i * 256 + t] = z4;
  }
}

// ---------------- async 16B global -> LDS ----------------
DEVI void gl_lds16(const unsigned short* gp, const unsigned short* lp) {
  __builtin_amdgcn_global_load_lds(
      (const __attribute__((address_space(1))) void*)gp,
      (__attribute__((address_space(3))) void*)lp, 16, 0, 0);
}

// Stage one half-tile from persistent streams; advance streams +128B (+1 K-tile).
// gX[q][j] holds the fully swizzled per-lane global addr; dX[q][j] the LDS
// ushort offset within a buffer. BUF is the buffer base (0 or 16384 ushorts).
#define STAGE_A(q, BUF)                                                       \
  do {                                                                        \
    gl_lds16(gA[q][0], AsF + (BUF) + dA[q][0]);                               \
    gl_lds16(gA[q][1], AsF + (BUF) + dA[q][1]);                               \
    gA[q][0] += 64; gA[q][1] += 64;                                           \
  } while (0)
#define STAGE_B(q, BUF)                                                       \
  do {                                                                        \
    gl_lds16(gB[q][0], BsF + (BUF) + dB[q][0]);                               \
    gl_lds16(gB[q][1], BsF + (BUF) + dB[q][1]);                               \
    gB[q][0] += 64; gB[q][1] += 64;                                           \
  } while (0)

// Fragment loads: base ptr + compile-time immediate only.
#define READ_A(MH)                                                            \
  _Pragma("unroll") for (int ms = 0; ms < 4; ++ms) {                          \
    af[0][ms] = *(const bf16x8*)(pA0 + (MH) * 8192 + ms * 2048);              \
    af[1][ms] = *(const bf16x8*)(pA1 + (MH) * 8192 + ms * 2048);              \
  }
#define READ_B(DST, NH)                                                       \
  _Pragma("unroll") for (int ns = 0; ns < 2; ++ns) {                          \
    DST[0][ns] = *(const bf16x8*)(pB0 + (NH) * 4096 + ns * 2048);             \
    DST[1][ns] = *(const bf16x8*)(pB1 + (NH) * 4096 + ns * 2048);             \
  }

// 16 MFMAs for one C-quadrant (MH,NH) using held fragments.
#define MFMA_Q(MH, NH, BSET)                                                  \
  do {                                                                        \
    __builtin_amdgcn_s_setprio(1);                                            \
    _Pragma("unroll") for (int kk = 0; kk < 2; ++kk)                          \
    _Pragma("unroll") for (int ms = 0; ms < 4; ++ms)                          \
    _Pragma("unroll") for (int ns = 0; ns < 2; ++ns)                          \
      acc[(MH) * 4 + ms][(NH) * 2 + ns] =                                     \
          __builtin_amdgcn_mfma_f32_16x16x32_bf16(                            \
              af[kk][ms], BSET[kk][ns], acc[(MH) * 4 + ms][(NH) * 2 + ns],    \
              0, 0, 0);                                                       \
    __builtin_amdgcn_s_setprio(0);                                            \
  } while (0)

#define WAITV4 asm volatile("s_waitcnt vmcnt(4)" ::: "memory")
#define WAITV0 asm volatile("s_waitcnt vmcnt(0)" ::: "memory")
#define SBAR __builtin_amdgcn_s_barrier()

// ---------------- C = A * Bt^T  (both bf16 row-major, K-major rows) ----------------
// 256x256 tile, BK=64, 8 waves (2M x 4N, 128x64 each), 128KiB dbuf LDS.
// EPI: 4 = fused QKV (sel=blockIdx.y>>2): Q (x+b)/32, K x+b, V -> Vt[b][d][k]
//      2 = P = exp(S) masked, bf16; atomic row sums -> lsum
//      3 = O = (P*V) * 1/lvec[row], f32
template <int EPI>
__global__ __launch_bounds__(512, 2) void k_gemm(
    const unsigned short* __restrict__ A, const unsigned short* __restrict__ Bt,
    void* __restrict__ Cv,
    const float* __restrict__ bias_q, const float* __restrict__ bias_k,
    const float* __restrict__ bias_v,
    const float* __restrict__ lvec, float* __restrict__ lsum,
    const int* __restrict__ mask,
    long aZ, long bZ, int ldA, int ldB, int kIters)
{
  // One buffer = 256 rows x 64 cols bf16 = 16384 ushorts (32KB). Two buffers
  // per operand -> 2*256*64 ushorts (64KB) each, 128KB total. BUF stride is
  // 16384 ushorts. (Round-7's fatal typo: 2*128*64 here.)
  __shared__ __attribute__((aligned(16))) unsigned short AsF[2 * 256 * 64];
  __shared__ __attribute__((aligned(16))) unsigned short BsF[2 * 256 * 64];
  const int tid = threadIdx.x, w = tid >> 6, l = tid & 63;
  const int quad = l >> 4, l15 = l & 15;
  const int wr = w & 1, wc = w >> 1;           // 2M x 4N wave grid
  const int wm = wr * 128, wn = wc * 64;
  const int m0 = blockIdx.x * 256;
  const int z = blockIdx.z;

  int n0, sel = 0;
  if constexpr (EPI == 4) { sel = blockIdx.y >> 2; n0 = (blockIdx.y & 3) * 256; }
  else n0 = blockIdx.y * 256;

  const unsigned short* Az = A + (size_t)z * aZ;
  const unsigned short* Bz = (EPI == 4) ? (Bt + ((size_t)sel << 20))
                                        : (Bt + (size_t)z * bZ);

  // ---- hoisted stage streams: per-lane swizzled global addrs + LDS offsets ----
  const int lr = l >> 3, uu = (l & 7) ^ lr;    // stage swizzle (row bases %8==0)
  const unsigned short* gA[2][2]; const unsigned short* gB[2][2];
  int dA[2][2], dB[2][2];
#pragma unroll
  for (int q = 0; q < 2; ++q)
#pragma unroll
    for (int j = 0; j < 2; ++j) {
      int slot = w * 2 + j;
      int rA = (slot >> 3) * 128 + q * 64 + (slot & 7) * 8;
      int rB = (slot >> 2) * 64 + q * 32 + (slot & 3) * 8;
      gA[q][j] = Az + (size_t)(m0 + rA + lr) * ldA + uu * 8;
      gB[q][j] = Bz + (size_t)(n0 + rB + lr) * ldB + uu * 8;
      dA[q][j] = rA * 64; dB[q][j] = rB * 64;
    }

  // ---- hoisted fragment-read byte offsets (frag swizzle (rr&7)==l15&7) ----
  const int cc0 = quad ^ (l15 & 7), cc1 = cc0 ^ 4;
  const int aoffA0 = (wm + l15) * 128 + cc0 * 16;
  const int aoffA1 = (wm + l15) * 128 + cc1 * 16;
  const int aoffB0 = (wn + l15) * 128 + cc0 * 16;
  const int aoffB1 = (wn + l15) * 128 + cc1 * 16;

  floatx4 acc[8][4];
#pragma unroll
  for (int i = 0; i < 8; ++i)
#pragma unroll
    for (int j = 0; j < 4; ++j) { floatx4 zz = {0.f, 0.f, 0.f, 0.f}; acc[i][j] = zz; }

  // -------- prologue: tile0 full + AH0/BH0(1); tile0 guaranteed landed --------
  STAGE_A(0, 0); STAGE_B(0, 0);            // AH0(0), BH0(0)
  STAGE_A(1, 0); STAGE_B(1, 0);            // AH1(0), BH1(0)
  if (kIters > 1) {
    STAGE_A(0, 16384); STAGE_B(0, 16384);  // AH0(1), BH0(1)
    WAITV4;
  } else {
    WAITV0;
  }
  SBAR;

  // -------- main loop: 4 phases/K-tile, reg-held frags, vmcnt(4)@p4 only ----
#pragma unroll 2
  for (int kt = 0; kt < kIters; ++kt) {
    const int ob = (kt & 1) ? 16384 : 0;   // current buffer (ushort offset)
    const int on = ob ^ 16384;             // next buffer
    const char* pA0 = (const char*)(AsF + ob) + aoffA0;
    const char* pA1 = (const char*)(AsF + ob) + aoffA1;
    const char* pB0 = (const char*)(BsF + ob) + aoffB0;
    const char* pB1 = (const char*)(BsF + ob) + aoffB1;
    bf16x8 af[2][4], bfr0[2][2], bfr1[2][2];

    // ---- p1: Q(0,0).  reads AH0+BH0 (12); stage AH1(t+1) -> bn ----
    READ_A(0); READ_B(bfr0, 0);
    if (kt + 1 < kIters) STAGE_A(1, on);
    SBAR;
    MFMA_Q(0, 0, bfr0);
    SBAR;
    // ---- p2: Q(0,1).  reads BH1 (4, af held); stage BH1(t+1) -> bn ----
    READ_B(bfr1, 1);
    if (kt + 1 < kIters) STAGE_B(1, on);
    SBAR;
    MFMA_Q(0, 1, bfr1);
    SBAR;
    // ---- p3: Q(1,1).  reads AH1 (8, bfr1 held); stage AH0(t+2) -> bc ----
    READ_A(1);
    if (kt + 2 < kIters) STAGE_A(0, ob);
    SBAR;
    MFMA_Q(1, 1, bfr1);
    SBAR;
    // ---- p4: Q(1,0).  NO reads (af, bfr0 held); stage BH0(t+2) -> bc ----
    if (kt + 2 < kIters) STAGE_B(0, ob);
    SBAR;
    MFMA_Q(1, 0, bfr0);
    if (kt + 2 < kIters) { WAITV4; } else { WAITV0; }
    SBAR;
  }

  // epilogue: C/D layout col = lane&15, row = quad*4 + reg  [m89/m91]
  if constexpr (EPI == 4) {
    unsigned short* C = (unsigned short*)Cv + ((size_t)sel << 24);
    const float* bs = sel == 0 ? bias_q : (sel == 1 ? bias_k : bias_v);
    if (sel < 2) {
      float sc = sel == 0 ? 0.03125f : 1.0f;
#pragma unroll
      for (int ns = 0; ns < 4; ++ns) {
        int n_g = n0 + wn + ns * 16 + l15;
        float bv = bs[n_g];
#pragma unroll
        for (int ms = 0; ms < 8; ++ms) {
          int mb = m0 + wm + ms * 16 + quad * 4;
#pragma unroll
          for (int r = 0; r < 4; ++r)
            C[(size_t)(mb + r) * 1024 + n_g] = f2bf((acc[ms][ns][r] + bv) * sc);
        }
      }
    } else {
      // V -> Vt[b][d][k]: the 4 r-values are CONSECUTIVE in k -> pack 8B stores
#pragma unroll
      for (int ns = 0; ns < 4; ++ns) {
        int n_g = n0 + wn + ns * 16 + l15;
        float bv = bs[n_g];
#pragma unroll
        for (int ms = 0; ms < 8; ++ms) {
          int m_g = m0 + wm + ms * 16 + quad * 4;   // r=0 element
          int bb = m_g >> 11, key = m_g & 2047;
          ushort4 pk;
          pk.x = f2bf(acc[ms][ns][0] + bv);
          pk.y = f2bf(acc[ms][ns][1] + bv);
          pk.z = f2bf(acc[ms][ns][2] + bv);
          pk.w = f2bf(acc[ms][ns][3] + bv);
          *(ushort4*)&C[((size_t)bb << 21) + ((size_t)n_g << 11) + key] = pk;
        }
      }
    }
  } else if constexpr (EPI == 2) {
    // P = exp(S) (max-free: |S| <= ~6), masked; atomic rowsums
    unsigned short* C = (unsigned short*)Cv + (size_t)z * 4194304;
    const int* mz = mask + z * 2048;
    float rowsum[8][4];
#pragma unroll
    for (int ms = 0; ms < 8; ++ms)
#pragma unroll
      for (int r = 0; r < 4; ++r) rowsum[ms][r] = 0.f;
#pragma unroll
    for (int ns = 0; ns < 4; ++ns) {
      int n_g = n0 + wn + ns * 16 + l15;
      int mv = mz[n_g];
#pragma unroll
      for (int ms = 0; ms < 8; ++ms) {
#pragma unroll
        for (int r = 0; r < 4; ++r) {
          int m_g = m0 + wm + ms * 16 + quad * 4 + r;
          float e = mv ? __expf(acc[ms][ns][r]) : 0.f;
          unsigned short pb = f2bf(e);
          C[(size_t)m_g * 2048 + n_g] = pb;
          rowsum[ms][r] += bf2f(pb);
        }
      }
    }
#pragma unroll
    for (int ms = 0; ms < 8; ++ms) {
#pragma unroll
      for (int r = 0; r < 4; ++r) {
        float s = rowsum[ms][r];
#pragma unroll
        for (int off = 1; off < 16; off <<= 1) s += __shfl_xor(s, off);
        if (l15 == 0) {
          int m_g = m0 + wm + ms * 16 + quad * 4 + r;
          atomicAdd(&lsum[z * 2048 + m_g], s);
        }
      }
    }
  } else {  // EPI == 3: O = (P*V)/l
    float* C = (float*)Cv + (size_t)z * 2048 * 1024;
    const float* lz = lvec + z * 2048;
#pragma unroll
    for (int ms = 0; ms < 8; ++ms) {
#pragma unroll
      for (int r = 0; r < 4; ++r) {
        int m_g = m0 + wm + ms * 16 + quad * 4 + r;
        float lw = lz[m_g];
        float inv = lw > 0.f ? 1.f / lw : 0.f;
#pragma unroll
        for (int ns = 0; ns < 4; ++ns) {
          int n_g = n0 + wn + ns * 16 + l15;
          C[(size_t)m_g * 1024 + n_g] = acc[ms][ns][r] * inv;
        }
      }
    }
  }
}

extern "C" void kernel_launch(void* const* d_in, const int* in_sizes, int n_in,
                              void* d_out, int out_size, void* d_ws, size_t ws_size,
                              hipStream_t stream) {
  const float* X    = (const float*)d_in[0];
  const int*   mask = (const int*)d_in[1];
  const float* Wq   = (const float*)d_in[2];
  const float* bq   = (const float*)d_in[3];
  const float* Wk   = (const float*)d_in[4];
  const float* bk   = (const float*)d_in[5];
  const float* Wv   = (const float*)d_in[6];
  const float* bv   = (const float*)d_in[7];
  float* out = (float*)d_out;

  constexpr size_t SZ = (size_t)16384 * 1024;
  unsigned short* Q    = (unsigned short*)d_ws;      // Q|K|Vt contiguous (sel<<24)
  float*          lvec = (float*)(Q + 3 * SZ);
  unsigned short* P    = (unsigned short*)(lvec + 16384);
  unsigned short* Xb   = P;               // overlaid: dead before P written
  unsigned short* Wt   = Xb + SZ;         // 3 x [1024][1024] bf16
  unsigned short* Vt   = Q + 2 * SZ;

  // 1. prep: X->bf16, W->Wt (bf16, transposed), lvec=0
  k_prep<<<dim3(17153), 256, 0, stream>>>(X, Xb, Wq, Wk, Wv, Wt, lvec);

  // 2. fused QKV projection (12 n-strips: 4 Q, 4 K, 4 V)
  k_gemm<4><<<dim3(64, 12, 1), 512, 0, stream>>>(
      Xb, Wt, (void*)Q, bq, bk, bv, nullptr, nullptr, nullptr,
      0, 0, 1024, 1024, 16);

  // 3. P = exp(Q K^T) masked + atomic row sums
  k_gemm<2><<<dim3(8, 8, 8), 512, 0, stream>>>(
      Q, Q + SZ, (void*)P, nullptr, nullptr, nullptr, nullptr, lvec, mask,
      2048 * 1024, 2048 * 1024, 1024, 1024, 16);

  // 4. O = (P V) / l  -> fp32 out
  k_gemm<3><<<dim3(8, 4, 8), 512, 0, stream>>>(
      P, Vt, (void*)out, nullptr, nullptr, nullptr, lvec, nullptr, nullptr,
      2048 * 2048, 1024 * 2048, 2048, 2048, 32);
}

// Round 5
// 401.759 us; speedup vs baseline: 1.0351x; 1.0351x over previous
//
#include <hip/hip_runtime.h>
#include <stdint.h>

#define DEVI __device__ __forceinline__

typedef __bf16 bf16x8 __attribute__((ext_vector_type(8)));
typedef float  floatx4 __attribute__((ext_vector_type(4)));

// B=8, S=2048, H=1024. M = B*S = 16384.
// ws: Q @0 (32MiB, pre-scaled log2e/32) | K @+32M | Vt @+64M ([8][1024 d][2048 k])
//     lvec @+96M (f32[16384]) | P @+96M+64K (bf16 [8][2048][2048]);
//     P region overlays Xb (32MiB) + Wt (6MiB), dead before P written.
//
// Round-9: round-8 measured all three GEMMs ~131us, MfmaUtil 32%, VALU 18%,
// ~50% of cycles idle on barrier/lgkm overhead (F~1000cy paid 4x/K-tile).
// Read-ahead across barriers is register-infeasible (244/256 budget at 8
// waves/CU). This round: MERGE PHASES PAIRWISE -> 2 phases/K-tile, 4 barriers
// instead of 8, no new registers (peak frag liveness 64 VGPR, same as before):
//   P12: reads A0+B0+B1 (16 ds_reads), stage AH1,BH1(t+1)->bn, SBAR,
//        32 MFMA (Q00,Q01) one setprio region, SBAR
//   P34: reads A1 (8), stage AH0,BH0(t+2)->bc, SBAR,
//        32 MFMA (Q11,Q10), vmcnt(4), SBAR
// Wait ledger (re-derived): entering tile t: 4 outstanding {AH0,BH0}(t+1).
// P12 +4 {AH1,BH1}(t+1), P34 +4 {AH0,BH0}(t+2) = 12; vmcnt(4) retires 8
// oldest = all of tile t+1 exactly; leaves {AH0,BH0}(t+2). Tails: at
// kt=kI-2 nothing staged in P34 -> vmcnt(0) retires all of kI-1. Same
// condition `kt+2<kIters ? V4 : V0` as round-8.
// WAR safety: P34's stage into bc-AH0/ bc-BH0 vs same-phase reads from
// bc-AH1 (disjoint regions); bn stages vs bn reads separated by vmcnt+SBAR.
// Also: Q pre-scale now log2e/32 so EPI2 epilogue uses raw v_exp_f32 (2^x).
// (Kept: do NOT replace with 32x32 MFMA, LDS-staged epilogue, or B-direct
// loads — all measured regressions in earlier rounds.)

DEVI unsigned short f2bf(float f) {
  union { float f; uint32_t u; } x; x.f = f;
  return (unsigned short)((x.u + 0x7fffu + ((x.u >> 16) & 1u)) >> 16);
}
DEVI float bf2f(unsigned short s) {
  union { uint32_t u; float f; } x; x.u = ((uint32_t)s) << 16;
  return x.f;
}

// ---------------- fused prep: X->bf16, 3x W transpose->bf16, lvec=0 ----------------
__global__ __launch_bounds__(256) void k_prep(
    const float* __restrict__ X, unsigned short* __restrict__ Xb,
    const float* __restrict__ Wq, const float* __restrict__ Wk,
    const float* __restrict__ Wv, unsigned short* __restrict__ Wt,
    float* __restrict__ lvec) {
  __shared__ float tile[64][65];
  int bx = blockIdx.x, t = threadIdx.x;
  if (bx < 16384) {                 // convert X: 4194304 float4 groups
    int i = bx * 256 + t;
    float4 v = ((const float4*)X)[i];
    ushort4 o;
    o.x = f2bf(v.x); o.y = f2bf(v.y); o.z = f2bf(v.z); o.w = f2bf(v.w);
    ((ushort4*)Xb)[i] = o;
  } else if (bx < 17152) {          // 3 x 256 transpose blocks
    int idx = bx - 16384;
    int sel = idx >> 8, b2 = idx & 255;
    const float* W = sel == 0 ? Wq : (sel == 1 ? Wk : Wv);
    unsigned short* Wo = Wt + ((size_t)sel << 20);
    int h0 = (b2 & 15) * 64, d0 = (b2 >> 4) * 64;
#pragma unroll
    for (int i = 0; i < 16; ++i) {
      int idx2 = i * 256 + t; int r = idx2 >> 6, c = idx2 & 63;
      tile[r][c] = W[(size_t)(h0 + r) * 1024 + d0 + c];
    }
    __syncthreads();
#pragma unroll
    for (int i = 0; i < 16; ++i) {
      int idx2 = i * 256 + t; int r = idx2 >> 6, c = idx2 & 63;
      Wo[(size_t)(d0 + r) * 1024 + h0 + c] = f2bf(tile[c][r]);
    }
  } else {                          // zero lvec (16384 f32)
    float4 z4 = {0.f, 0.f, 0.f, 0.f};
#pragma unroll
    for (int i = 0; i < 16; ++i) ((float4*)lvec)[i * 256 + t] = z4;
  }
}

// ---------------- async 16B global -> LDS ----------------
DEVI void gl_lds16(const unsigned short* gp, const unsigned short* lp) {
  __builtin_amdgcn_global_load_lds(
      (const __attribute__((address_space(1))) void*)gp,
      (__attribute__((address_space(3))) void*)lp, 16, 0, 0);
}

// Stage one half-tile from persistent streams; advance streams +128B (+1 K-tile).
// gX[q][j]: fully swizzled per-lane global addr; dX[q][j]: wave-uniform LDS
// ushort offset within a buffer. BUF = buffer base (0 or 16384 ushorts).
#define STAGE_A(q, BUF)                                                       \
  do {                                                                        \
    gl_lds16(gA[q][0], AsF + (BUF) + dA[q][0]);                               \
    gl_lds16(gA[q][1], AsF + (BUF) + dA[q][1]);                               \
    gA[q][0] += 64; gA[q][1] += 64;                                           \
  } while (0)
#define STAGE_B(q, BUF)                                                       \
  do {                                                                        \
    gl_lds16(gB[q][0], BsF + (BUF) + dB[q][0]);                               \
    gl_lds16(gB[q][1], BsF + (BUF) + dB[q][1]);                               \
    gB[q][0] += 64; gB[q][1] += 64;                                           \
  } while (0)

// Fragment loads: base ptr + compile-time immediate only.
#define READ_A(MH)                                                            \
  _Pragma("unroll") for (int ms = 0; ms < 4; ++ms) {                          \
    af[0][ms] = *(const bf16x8*)(pA0 + (MH) * 8192 + ms * 2048);              \
    af[1][ms] = *(const bf16x8*)(pA1 + (MH) * 8192 + ms * 2048);              \
  }
#define READ_B(DST, NH)                                                       \
  _Pragma("unroll") for (int ns = 0; ns < 2; ++ns) {                          \
    DST[0][ns] = *(const bf16x8*)(pB0 + (NH) * 4096 + ns * 2048);             \
    DST[1][ns] = *(const bf16x8*)(pB1 + (NH) * 4096 + ns * 2048);             \
  }

// 16 MFMAs for one C-quadrant (no setprio; caller wraps the cluster).
#define MFMA_Q(MH, NH, BSET)                                                  \
  _Pragma("unroll") for (int kk = 0; kk < 2; ++kk)                            \
  _Pragma("unroll") for (int ms = 0; ms < 4; ++ms)                            \
  _Pragma("unroll") for (int ns = 0; ns < 2; ++ns)                            \
    acc[(MH) * 4 + ms][(NH) * 2 + ns] =                                       \
        __builtin_amdgcn_mfma_f32_16x16x32_bf16(                              \
            af[kk][ms], BSET[kk][ns], acc[(MH) * 4 + ms][(NH) * 2 + ns],      \
            0, 0, 0);

#define PRIO1 __builtin_amdgcn_s_setprio(1)
#define PRIO0 __builtin_amdgcn_s_setprio(0)
#define WAITV4 asm volatile("s_waitcnt vmcnt(4)" ::: "memory")
#define WAITV0 asm volatile("s_waitcnt vmcnt(0)" ::: "memory")
#define SBAR __builtin_amdgcn_s_barrier()

// ---------------- C = A * Bt^T  (both bf16 row-major, K-major rows) ----------------
// 256x256 tile, BK=64, 8 waves (2M x 4N, 128x64 each), 128KiB dbuf LDS.
// EPI: 4 = fused QKV (sel=blockIdx.y>>2): Q (x+b)*log2e/32, K x+b, V -> Vt[b][d][k]
//      2 = P = exp2(S) masked, bf16; atomic row sums -> lsum
//      3 = O = (P*V) * 1/lvec[row], f32
template <int EPI>
__global__ __launch_bounds__(512, 2) void k_gemm(
    const unsigned short* __restrict__ A, const unsigned short* __restrict__ Bt,
    void* __restrict__ Cv,
    const float* __restrict__ bias_q, const float* __restrict__ bias_k,
    const float* __restrict__ bias_v,
    const float* __restrict__ lvec, float* __restrict__ lsum,
    const int* __restrict__ mask,
    long aZ, long bZ, int ldA, int ldB, int kIters)
{
  // One buffer = 256 rows x 64 cols bf16 = 16384 ushorts (32KB); dbuf per
  // operand -> 2*256*64 each, 128KB total. BUF stride 16384 ushorts.
  __shared__ __attribute__((aligned(16))) unsigned short AsF[2 * 256 * 64];
  __shared__ __attribute__((aligned(16))) unsigned short BsF[2 * 256 * 64];
  const int tid = threadIdx.x, w = tid >> 6, l = tid & 63;
  const int quad = l >> 4, l15 = l & 15;
  const int wr = w & 1, wc = w >> 1;           // 2M x 4N wave grid
  const int wm = wr * 128, wn = wc * 64;
  const int m0 = blockIdx.x * 256;
  const int z = blockIdx.z;

  int n0, sel = 0;
  if constexpr (EPI == 4) { sel = blockIdx.y >> 2; n0 = (blockIdx.y & 3) * 256; }
  else n0 = blockIdx.y * 256;

  const unsigned short* Az = A + (size_t)z * aZ;
  const unsigned short* Bz = (EPI == 4) ? (Bt + ((size_t)sel << 20))
                                        : (Bt + (size_t)z * bZ);

  // ---- hoisted stage streams: per-lane swizzled global addrs + LDS offsets ----
  const int lr = l >> 3, uu = (l & 7) ^ lr;    // stage swizzle (row bases %8==0)
  const unsigned short* gA[2][2]; const unsigned short* gB[2][2];
  int dA[2][2], dB[2][2];
#pragma unroll
  for (int q = 0; q < 2; ++q)
#pragma unroll
    for (int j = 0; j < 2; ++j) {
      int slot = w * 2 + j;
      int rA = (slot >> 3) * 128 + q * 64 + (slot & 7) * 8;
      int rB = (slot >> 2) * 64 + q * 32 + (slot & 3) * 8;
      gA[q][j] = Az + (size_t)(m0 + rA + lr) * ldA + uu * 8;
      gB[q][j] = Bz + (size_t)(n0 + rB + lr) * ldB + uu * 8;
      dA[q][j] = rA * 64; dB[q][j] = rB * 64;
    }

  // ---- hoisted fragment-read byte offsets (frag swizzle (rr&7)==l15&7) ----
  const int cc0 = quad ^ (l15 & 7), cc1 = cc0 ^ 4;
  const int aoffA0 = (wm + l15) * 128 + cc0 * 16;
  const int aoffA1 = (wm + l15) * 128 + cc1 * 16;
  const int aoffB0 = (wn + l15) * 128 + cc0 * 16;
  const int aoffB1 = (wn + l15) * 128 + cc1 * 16;

  floatx4 acc[8][4];
#pragma unroll
  for (int i = 0; i < 8; ++i)
#pragma unroll
    for (int j = 0; j < 4; ++j) { floatx4 zz = {0.f, 0.f, 0.f, 0.f}; acc[i][j] = zz; }

  // -------- prologue: tile0 full + AH0/BH0(1); tile0 guaranteed landed --------
  STAGE_A(0, 0); STAGE_B(0, 0);            // AH0(0), BH0(0)
  STAGE_A(1, 0); STAGE_B(1, 0);            // AH1(0), BH1(0)
  if (kIters > 1) {
    STAGE_A(0, 16384); STAGE_B(0, 16384);  // AH0(1), BH0(1)
    WAITV4;
  } else {
    WAITV0;
  }
  SBAR;

  // -------- main loop: 2 merged phases/K-tile, vmcnt(4)@P34 only ----
#pragma unroll 2
  for (int kt = 0; kt < kIters; ++kt) {
    const int ob = (kt & 1) ? 16384 : 0;   // current buffer (ushort offset)
    const int on = ob ^ 16384;             // next buffer
    const char* pA0 = (const char*)(AsF + ob) + aoffA0;
    const char* pA1 = (const char*)(AsF + ob) + aoffA1;
    const char* pB0 = (const char*)(BsF + ob) + aoffB0;
    const char* pB1 = (const char*)(BsF + ob) + aoffB1;
    bf16x8 af[2][4], bfr0[2][2], bfr1[2][2];

    // ---- P12: Q(0,0)+Q(0,1). reads A0+B0+B1 (16); stage AH1,BH1(t+1)->bn ----
    READ_A(0); READ_B(bfr0, 0); READ_B(bfr1, 1);
    if (kt + 1 < kIters) { STAGE_A(1, on); STAGE_B(1, on); }
    SBAR;
    PRIO1;
    MFMA_Q(0, 0, bfr0);
    MFMA_Q(0, 1, bfr1);
    PRIO0;
    SBAR;
    // ---- P34: Q(1,1)+Q(1,0). reads A1 (8); stage AH0,BH0(t+2)->bc ----
    READ_A(1);
    if (kt + 2 < kIters) { STAGE_A(0, ob); STAGE_B(0, ob); }
    SBAR;
    PRIO1;
    MFMA_Q(1, 1, bfr1);
    MFMA_Q(1, 0, bfr0);
    PRIO0;
    if (kt + 2 < kIters) { WAITV4; } else { WAITV0; }
    SBAR;
  }

  // epilogue: C/D layout col = lane&15, row = quad*4 + reg  [m89/m91]
  if constexpr (EPI == 4) {
    unsigned short* C = (unsigned short*)Cv + ((size_t)sel << 24);
    const float* bs = sel == 0 ? bias_q : (sel == 1 ? bias_k : bias_v);
    if (sel < 2) {
      // Q scale folds 1/sqrt(H)=1/32 AND log2(e) so EPI2 can use raw v_exp_f32.
      float sc = sel == 0 ? 0.045084439f : 1.0f;   // log2e/32
#pragma unroll
      for (int ns = 0; ns < 4; ++ns) {
        int n_g = n0 + wn + ns * 16 + l15;
        float bv = bs[n_g];
#pragma unroll
        for (int ms = 0; ms < 8; ++ms) {
          int mb = m0 + wm + ms * 16 + quad * 4;
#pragma unroll
          for (int r = 0; r < 4; ++r)
            C[(size_t)(mb + r) * 1024 + n_g] = f2bf((acc[ms][ns][r] + bv) * sc);
        }
      }
    } else {
      // V -> Vt[b][d][k]: the 4 r-values are CONSECUTIVE in k -> pack 8B stores
#pragma unroll
      for (int ns = 0; ns < 4; ++ns) {
        int n_g = n0 + wn + ns * 16 + l15;
        float bv = bs[n_g];
#pragma unroll
        for (int ms = 0; ms < 8; ++ms) {
          int m_g = m0 + wm + ms * 16 + quad * 4;   // r=0 element
          int bb = m_g >> 11, key = m_g & 2047;
          ushort4 pk;
          pk.x = f2bf(acc[ms][ns][0] + bv);
          pk.y = f2bf(acc[ms][ns][1] + bv);
          pk.z = f2bf(acc[ms][ns][2] + bv);
          pk.w = f2bf(acc[ms][ns][3] + bv);
          *(ushort4*)&C[((size_t)bb << 21) + ((size_t)n_g << 11) + key] = pk;
        }
      }
    }
  } else if constexpr (EPI == 2) {
    // P = 2^S (S pre-scaled by log2e; max-free: |S| small), masked; rowsums
    unsigned short* C = (unsigned short*)Cv + (size_t)z * 4194304;
    const int* mz = mask + z * 2048;
    float rowsum[8][4];
#pragma unroll
    for (int ms = 0; ms < 8; ++ms)
#pragma unroll
      for (int r = 0; r < 4; ++r) rowsum[ms][r] = 0.f;
#pragma unroll
    for (int ns = 0; ns < 4; ++ns) {
      int n_g = n0 + wn + ns * 16 + l15;
      int mv = mz[n_g];
#pragma unroll
      for (int ms = 0; ms < 8; ++ms) {
#pragma unroll
        for (int r = 0; r < 4; ++r) {
          int m_g = m0 + wm + ms * 16 + quad * 4 + r;
          float e;
          asm("v_exp_f32 %0, %1" : "=v"(e) : "v"(acc[ms][ns][r]));  // 2^x
          e = mv ? e : 0.f;
          unsigned short pb = f2bf(e);
          C[(size_t)m_g * 2048 + n_g] = pb;
          rowsum[ms][r] += bf2f(pb);
        }
      }
    }
#pragma unroll
    for (int ms = 0; ms < 8; ++ms) {
#pragma unroll
      for (int r = 0; r < 4; ++r) {
        float s = rowsum[ms][r];
#pragma unroll
        for (int off = 1; off < 16; off <<= 1) s += __shfl_xor(s, off);
        if (l15 == 0) {
          int m_g = m0 + wm + ms * 16 + quad * 4 + r;
          atomicAdd(&lsum[z * 2048 + m_g], s);
        }
      }
    }
  } else {  // EPI == 3: O = (P*V)/l
    float* C = (float*)Cv + (size_t)z * 2048 * 1024;
    const float* lz = lvec + z * 2048;
#pragma unroll
    for (int ms = 0; ms < 8; ++ms) {
#pragma unroll
      for (int r = 0; r < 4; ++r) {
        int m_g = m0 + wm + ms * 16 + quad * 4 + r;
        float lw = lz[m_g];
        float inv = lw > 0.f ? 1.f / lw : 0.f;
#pragma unroll
        for (int ns = 0; ns < 4; ++ns) {
          int n_g = n0 + wn + ns * 16 + l15;
          C[(size_t)m_g * 1024 + n_g] = acc[ms][ns][r] * inv;
        }
      }
    }
  }
}

extern "C" void kernel_launch(void* const* d_in, const int* in_sizes, int n_in,
                              void* d_out, int out_size, void* d_ws, size_t ws_size,
                              hipStream_t stream) {
  const float* X    = (const float*)d_in[0];
  const int*   mask = (const int*)d_in[1];
  const float* Wq   = (const float*)d_in[2];
  const float* bq   = (const float*)d_in[3];
  const float* Wk   = (const float*)d_in[4];
  const float* bk   = (const float*)d_in[5];
  const float* Wv   = (const float*)d_in[6];
  const float* bv   = (const float*)d_in[7];
  float* out = (float*)d_out;

  constexpr size_t SZ = (size_t)16384 * 1024;
  unsigned short* Q    = (unsigned short*)d_ws;      // Q|K|Vt contiguous (sel<<24)
  float*          lvec = (float*)(Q + 3 * SZ);
  unsigned short* P    = (unsigned short*)(lvec + 16384);
  unsigned short* Xb   = P;               // overlaid: dead before P written
  unsigned short* Wt   = Xb + SZ;         // 3 x [1024][1024] bf16
  unsigned short* Vt   = Q + 2 * SZ;

  // 1. prep: X->bf16, W->Wt (bf16, transposed), lvec=0
  k_prep<<<dim3(17153), 256, 0, stream>>>(X, Xb, Wq, Wk, Wv, Wt, lvec);

  // 2. fused QKV projection (12 n-strips: 4 Q, 4 K, 4 V)
  k_gemm<4><<<dim3(64, 12, 1), 512, 0, stream>>>(
      Xb, Wt, (void*)Q, bq, bk, bv, nullptr, nullptr, nullptr,
      0, 0, 1024, 1024, 16);

  // 3. P = 2^(Q K^T * log2e/32) masked + atomic row sums
  k_gemm<2><<<dim3(8, 8, 8), 512, 0, stream>>>(
      Q, Q + SZ, (void*)P, nullptr, nullptr, nullptr, nullptr, lvec, mask,
      2048 * 1024, 2048 * 1024, 1024, 1024, 16);

  // 4. O = (P V) / l  -> fp32 out
  k_gemm<3><<<dim3(8, 4, 8), 512, 0, stream>>>(
      P, Vt, (void*)out, nullptr, nullptr, nullptr, lvec, nullptr, nullptr,
      2048 * 2048, 1024 * 2048, 2048, 2048, 32);
}